// Round 1
// baseline (597.463 us; speedup 1.0000x reference)
//
#include <hip/hip_runtime.h>
#include <hip/hip_bf16.h>
#include <stdint.h>
#include <stddef.h>

typedef __attribute__((ext_vector_type(8))) short short8;
typedef __attribute__((ext_vector_type(4))) float f32x4;

#define B_ROWS 1024
#define ND 256
#define MT 128

__device__ __forceinline__ unsigned short f2bf(float x){
  unsigned u = __float_as_uint(x);
  return (unsigned short)((u + 0x7fffu + ((u >> 16) & 1u)) >> 16);
}
__device__ __forceinline__ float bf2f(unsigned short h){
  return __uint_as_float(((unsigned)h) << 16);
}

// ---------------------------------------------------------------------------
// Kernel 1: convert W (fp32 [K][256]) -> chunked bf16 hi/lo, layout [c][256][32]
// so that MFMA B-fragments are contiguous 16B runs (perfect global coalescing).
// ---------------------------------------------------------------------------
struct ConvArgs {
  const float* W[4];
  unsigned short* dstHi[4];
  unsigned short* dstLo[4];
  int K[4];
  int chBase[4];   // chunk index base per W
};

__global__ void conv_w_kernel(ConvArgs a){
  int cb = blockIdx.x;
  int w = 0;
  if (cb >= a.chBase[1]) w = 1;
  if (cb >= a.chBase[2]) w = 2;
  if (cb >= a.chBase[3]) w = 3;
  int c = cb - a.chBase[w];
  __shared__ float tile[32][257];
  const float* Wp = a.W[w];
  int K = a.K[w];
  int t = threadIdx.x;
  int r  = t >> 3;
  int c0 = (t & 7) * 32;
  int gk = c * 32 + r;
  if (gk < K){
    const float* src = Wp + (size_t)gk * ND + c0;
    #pragma unroll
    for (int j = 0; j < 32; j += 4){
      float4 v = *(const float4*)(src + j);
      tile[r][c0+j+0] = v.x; tile[r][c0+j+1] = v.y;
      tile[r][c0+j+2] = v.z; tile[r][c0+j+3] = v.w;
    }
  } else {
    #pragma unroll
    for (int j = 0; j < 32; ++j) tile[r][c0+j] = 0.f;
  }
  __syncthreads();
  int n = t;   // 0..255
  unsigned short hi[32], lo[32];
  #pragma unroll
  for (int k = 0; k < 32; ++k){
    float x = tile[k][n];
    unsigned short h = f2bf(x);
    hi[k] = h;
    lo[k] = f2bf(x - bf2f(h));
  }
  size_t base = ((size_t)c * ND + n) * 32;
  unsigned short* dh = a.dstHi[w] + base;
  unsigned short* dl = a.dstLo[w] + base;
  union { unsigned short u[8]; uint4 v; } pk;
  #pragma unroll
  for (int q = 0; q < 4; ++q){
    #pragma unroll
    for (int e = 0; e < 8; ++e) pk.u[e] = hi[q*8+e];
    *(uint4*)(dh + q*8) = pk.v;
    #pragma unroll
    for (int e = 0; e < 8; ++e) pk.u[e] = lo[q*8+e];
    *(uint4*)(dl + q*8) = pk.v;
  }
}

// ---------------------------------------------------------------------------
// Kernel 2: init the 10 embedding buffers with their biases (GEMM accumulates).
// ---------------------------------------------------------------------------
struct BiasArgs { float* emb; const float* b[10]; };

__global__ void bias_init_kernel(BiasArgs a){
  int idx = blockIdx.x * blockDim.x + threadIdx.x;  // one float4 per thread
  int g  = idx >> 16;          // 65536 float4 per (1024x256) buffer
  int wi = idx & 65535;
  int n4 = (wi & 63) * 4;
  const float* bp = a.b[g];
  float4 v; v.x = bp[n4]; v.y = bp[n4+1]; v.z = bp[n4+2]; v.w = bp[n4+3];
  *(float4*)(a.emb + (size_t)idx * 4) = v;
}

// ---------------------------------------------------------------------------
// Kernel 3: split-bf16 MFMA GEMM.  C[g] += X[g] @ W[g]  (fp32-accurate via
// hi*hi + hi*lo + lo*hi).  WG = 256 thr (4 waves), tile MT x 256, K-split with
// fp32 atomicAdd epilogue.  A staged fp32->bf16 hi/lo in padded LDS; B frags
// loaded straight from the chunked global layout (coalesced dwordx4).
// ---------------------------------------------------------------------------
struct GemmArgs {
  const float* X[10];
  const unsigned short* Wh[10];
  const unsigned short* Wl[10];
  float* C[10];
  int K[10];
  int nch[10];
  int ksplit[10];
  int wgBase[11];
};

__launch_bounds__(256, 2)
__global__ void gemm_kernel(GemmArgs a){
  __shared__ unsigned short Ah[MT][40];   // +8 pad: <=2-way bank aliasing (free)
  __shared__ unsigned short Al[MT][40];

  int bid = blockIdx.x;
  int g = 0;
  while (bid >= a.wgBase[g+1]) ++g;
  int loc = bid - a.wgBase[g];
  int mt = loc & 7;        // 8 m-tiles (1024/128)
  int ks = loc >> 3;
  int nch = a.nch[g];
  int ksp = a.ksplit[g];
  int q = nch / ksp, r = nch % ksp;
  int c0  = ks * q + (ks < r ? ks : r);
  int cnt = q + (ks < r ? 1 : 0);

  const float* X = a.X[g];
  int K = a.K[g];
  const unsigned short* Wh = a.Wh[g];
  const unsigned short* Wl = a.Wl[g];

  int t = threadIdx.x;
  int lane = t & 63, w = t >> 6;
  int ln15 = lane & 15, kg = lane >> 4;
  int rowbase = mt * MT;
  int srow = t >> 1, sseg = (t & 1) * 16;
  const float* xrow = X + (size_t)(rowbase + srow) * K;

  f32x4 acc[8][4];
  #pragma unroll
  for (int i = 0; i < 8; ++i)
    #pragma unroll
    for (int j = 0; j < 4; ++j) acc[i][j] = (f32x4){0.f,0.f,0.f,0.f};

  for (int ci = 0; ci < cnt; ++ci){
    int c = c0 + ci;
    // ---- issue B fragment loads first (latency hides under A staging) ----
    short8 bh[4], bl[4];
    size_t cb = (size_t)c * (ND * 32);
    #pragma unroll
    for (int j = 0; j < 4; ++j){
      size_t offs = cb + (size_t)(w*64 + j*16 + ln15) * 32 + kg*8;
      bh[j] = *(const short8*)(Wh + offs);
      bl[j] = *(const short8*)(Wl + offs);
    }
    // ---- stage A chunk: fp32 -> bf16 hi/lo ----
    int gk0 = c * 32 + sseg;
    float xv[16];
    if (gk0 + 16 <= K){
      #pragma unroll
      for (int j = 0; j < 16; j += 4){
        float4 v = *(const float4*)(xrow + gk0 + j);
        xv[j] = v.x; xv[j+1] = v.y; xv[j+2] = v.z; xv[j+3] = v.w;
      }
    } else {
      #pragma unroll
      for (int j = 0; j < 16; ++j) xv[j] = (gk0 + j < K) ? xrow[gk0 + j] : 0.f;
    }
    unsigned short hh[16], ll[16];
    #pragma unroll
    for (int j = 0; j < 16; ++j){
      unsigned short h = f2bf(xv[j]);
      hh[j] = h;
      ll[j] = f2bf(xv[j] - bf2f(h));
    }
    __syncthreads();   // previous iteration's LDS reads complete
    union { unsigned short u[8]; uint4 v; } pk;
    #pragma unroll
    for (int q2 = 0; q2 < 2; ++q2){
      #pragma unroll
      for (int e = 0; e < 8; ++e) pk.u[e] = hh[q2*8+e];
      *(uint4*)&Ah[srow][sseg + q2*8] = pk.v;
      #pragma unroll
      for (int e = 0; e < 8; ++e) pk.u[e] = ll[q2*8+e];
      *(uint4*)&Al[srow][sseg + q2*8] = pk.v;
    }
    __syncthreads();
    // ---- MFMA ----
    #pragma unroll
    for (int i = 0; i < 8; ++i){
      const short8 ah = *(const short8*)&Ah[i*16 + ln15][kg*8];
      const short8 al = *(const short8*)&Al[i*16 + ln15][kg*8];
      #pragma unroll
      for (int j = 0; j < 4; ++j){
        acc[i][j] = __builtin_amdgcn_mfma_f32_16x16x32_bf16(ah, bh[j], acc[i][j], 0, 0, 0);
        acc[i][j] = __builtin_amdgcn_mfma_f32_16x16x32_bf16(ah, bl[j], acc[i][j], 0, 0, 0);
        acc[i][j] = __builtin_amdgcn_mfma_f32_16x16x32_bf16(al, bh[j], acc[i][j], 0, 0, 0);
      }
    }
  }
  // ---- epilogue: atomic accumulate (K-split partials) ----
  float* C = a.C[g];
  int crow0 = (lane >> 4) * 4;
  #pragma unroll
  for (int i = 0; i < 8; ++i){
    #pragma unroll
    for (int j = 0; j < 4; ++j){
      int col = w*64 + j*16 + ln15;
      #pragma unroll
      for (int rr = 0; rr < 4; ++rr){
        int row = rowbase + i*16 + crow0 + rr;
        atomicAdd(&C[(size_t)row * ND + col], acc[i][j][rr]);
      }
    }
  }
}

// ---------------------------------------------------------------------------
// Kernel 4: fused homo-attention + hete routing + final softmax.
// One WG per batch row; wave f owns facet f; d = lane. All reductions are
// 64-lane shfl_xor trees.
// ---------------------------------------------------------------------------
__device__ __forceinline__ float wsum(float v){
  #pragma unroll
  for (int m = 32; m; m >>= 1) v += __shfl_xor(v, m, 64);
  return v;
}

__global__ void fuse_kernel(const float* __restrict__ emb,
                            const float* __restrict__ homo_a,
                            float* __restrict__ out){
  int b = blockIdx.x;
  int t = threadIdx.x;
  int f = t >> 6;
  int d = t & 63;
  auto E = [&](int g){ return emb[((size_t)g * B_ROWS + b) * ND + t]; };

  float us = E(0), bs = E(1);
  float un[4], bn[4];
  #pragma unroll
  for (int i = 0; i < 4; ++i){ un[i] = E(2+i); bn[i] = E(6+i); }

  // homo attention: per-facet gated fusion
  float ul[4], blv[4];
  #pragma unroll
  for (int i = 0; i < 4; ++i){
    float as_ = homo_a[i*128 + d],     an_ = homo_a[i*128 + 64 + d];
    float sc  = wsum(us*as_ + un[i]*an_);
    sc = sc > 0.f ? sc : 0.2f*sc;
    float alp = 1.f / (1.f + expf(-sc));
    ul[i] = us + alp*un[i];
    float as2 = homo_a[(4+i)*128 + d], an2 = homo_a[(4+i)*128 + 64 + d];
    float sc2 = wsum(bs*as2 + bn[i]*an2);
    sc2 = sc2 > 0.f ? sc2 : 0.2f*sc2;
    float alp2 = 1.f / (1.f + expf(-sc2));
    blv[i] = bs + alp2*bn[i];
  }

  // normalize self (NOTE: business hete also uses user_embed as self — faithful)
  float u0 = us / (sqrtf(wsum(us*us)) + 1e-8f);
  float zu[4], zb[4];
  #pragma unroll
  for (int i = 0; i < 4; ++i){
    zu[i] = ul[i]  / (sqrtf(wsum(ul[i]*ul[i]))   + 1e-8f);
    zb[i] = blv[i] / (sqrtf(wsum(blv[i]*blv[i])) + 1e-8f);
  }

  auto route = [&](float z0, float z1, float z2, float z3)->float{
    float u = u0;
    #pragma unroll
    for (int it = 0; it < 3; ++it){
      float d0 = wsum(u*z0), d1 = wsum(u*z1), d2 = wsum(u*z2), d3 = wsum(u*z3);
      float m = fmaxf(fmaxf(d0,d1), fmaxf(d2,d3));
      float e0 = expf(d0-m), e1 = expf(d1-m), e2 = expf(d2-m), e3 = expf(d3-m);
      float s = e0+e1+e2+e3;
      float nu = u0 + (e0*z0 + e1*z1 + e2*z2 + e3*z3) / s;
      u = nu / (sqrtf(wsum(nu*nu)) + 1e-8f);
    }
    return u;
  };

  float uu = route(zu[0], zu[1], zu[2], zu[3]);
  float ub = route(zb[0], zb[1], zb[2], zb[3]);

  float lg = wsum(uu*ub);
  __shared__ float sl[4];
  if (d == 0) sl[f] = lg;
  __syncthreads();
  if (t < 4){
    float l0 = sl[0], l1 = sl[1], l2 = sl[2], l3 = sl[3];
    float m = fmaxf(fmaxf(l0,l1), fmaxf(l2,l3));
    float den = expf(l0-m) + expf(l1-m) + expf(l2-m) + expf(l3-m);
    out[(size_t)b*4 + t] = expf(sl[t]-m) / den;
  }
}

// ---------------------------------------------------------------------------
extern "C" void kernel_launch(void* const* d_in, const int* in_sizes, int n_in,
                              void* d_out, int out_size, void* d_ws, size_t ws_size,
                              hipStream_t stream) {
  // inputs
  const float* X[10];
  for (int i = 0; i < 10; ++i) X[i] = (const float*)d_in[i];
  const float* Wm[4]   = { (const float*)d_in[10], (const float*)d_in[12],
                           (const float*)d_in[14], (const float*)d_in[16] };
  const float* bias[4] = { (const float*)d_in[11], (const float*)d_in[13],
                           (const float*)d_in[15], (const float*)d_in[17] };
  const float* homo_a  = (const float*)d_in[18];
  float* out = (float*)d_out;

  // workspace layout
  const size_t EMB_FLOATS = 10ull * B_ROWS * ND;            // 2,621,440
  float* emb = (float*)d_ws;
  unsigned short* wch = (unsigned short*)((char*)d_ws + EMB_FLOATS * 4);
  // per-W chunk counts: user 625, bus 625, city 32, cat 16
  const int nchW[4] = {625, 625, 32, 16};
  size_t off[8]; // hi/lo offsets per W
  {
    size_t o = 0;
    for (int w = 0; w < 4; ++w){
      off[2*w]   = o; o += (size_t)nchW[w] * ND * 32;   // hi
      off[2*w+1] = o; o += (size_t)nchW[w] * ND * 32;   // lo
    }
  }
  const int Kw[4] = {20000, 20000, 1000, 500};

  // ---- conv W ----
  ConvArgs ca;
  int cbase = 0;
  for (int w = 0; w < 4; ++w){
    ca.W[w] = Wm[w];
    ca.dstHi[w] = wch + off[2*w];
    ca.dstLo[w] = wch + off[2*w+1];
    ca.K[w] = Kw[w];
    ca.chBase[w] = cbase;
    cbase += nchW[w];
  }
  hipLaunchKernelGGL(conv_w_kernel, dim3(cbase), dim3(256), 0, stream, ca);

  // ---- bias init ----
  static const int biasOf[10] = {0,1,0,1,2,3,0,1,2,3};
  BiasArgs ba;
  ba.emb = emb;
  for (int g = 0; g < 10; ++g) ba.b[g] = bias[biasOf[g]];
  hipLaunchKernelGGL(bias_init_kernel, dim3((EMB_FLOATS/4)/256), dim3(256), 0, stream, ba);

  // ---- gemm ----
  static const int wOf[10]  = {0,1,0,1,2,3,0,1,2,3};
  static const int ksp[10]  = {10,10,10,10,2,1,10,10,2,1};
  GemmArgs ga;
  int base = 0;
  for (int g = 0; g < 10; ++g){
    ga.X[g]  = X[g];
    ga.Wh[g] = wch + off[2*wOf[g]];
    ga.Wl[g] = wch + off[2*wOf[g]+1];
    ga.C[g]  = emb + (size_t)g * B_ROWS * ND;
    ga.K[g]  = Kw[wOf[g]];
    ga.nch[g] = nchW[wOf[g]];
    ga.ksplit[g] = ksp[g];
    ga.wgBase[g] = base;
    base += 8 * ksp[g];
  }
  ga.wgBase[10] = base;   // 528
  hipLaunchKernelGGL(gemm_kernel, dim3(base), dim3(256), 0, stream, ga);

  // ---- fused attention/routing ----
  hipLaunchKernelGGL(fuse_kernel, dim3(B_ROWS), dim3(256), 0, stream, emb, homo_a, out);
}